// Round 3
// baseline (5467.772 us; speedup 1.0000x reference)
//
#include <hip/hip_runtime.h>
#include <hip/hip_bf16.h>
#include <cstdint>
#include <cstddef>

#define IN_DIM 512
#define OUT_DIM 256
#define BROWS 64              // rows per bucket
#define MAX_NB 1600           // >= ceil(100000/64)=1563

typedef __bf16 bf16x8 __attribute__((ext_vector_type(8)));
typedef float f32x4 __attribute__((ext_vector_type(4)));

__device__ __forceinline__ unsigned short f2bf(float f) {
    __bf16 h = (__bf16)f;
    return __builtin_bit_cast(unsigned short, h);
}
__device__ __forceinline__ float bf2f(unsigned short u) {
    unsigned int x = ((unsigned int)u) << 16;
    return __builtin_bit_cast(float, x);
}
__device__ __forceinline__ float selu(float x) {
    const float kScale = 1.0507009873554805f;
    const float kAlpha = 1.6732632423543772f;
    return (x > 0.f) ? kScale * x : kScale * kAlpha * (expf(x) - 1.f);
}

// ---------------- W convert + transpose: [512,256] f32 -> Wt [256,512] bf16 ----
__global__ void k_convW(const float* __restrict__ W, unsigned short* __restrict__ Wt) {
    int idx = blockIdx.x * 256 + threadIdx.x;
    int n = idx & (OUT_DIM - 1);
    int k = idx >> 8;
    if (k < IN_DIM) Wt[n * IN_DIM + k] = f2bf(W[k * OUT_DIM + n]);
}

// ---------------- GEMM: xw = features @ W, full-N 128x256 tile ----------------
__launch_bounds__(512, 2)
__global__ void k_gemm(const float* __restrict__ A, const unsigned short* __restrict__ Wt,
                       unsigned short* __restrict__ xw, int M) {
    __shared__ unsigned short lA[128 * 32];
    __shared__ unsigned short lB[256 * 32];
    const int t = threadIdx.x;
    const int wave = t >> 6, lane = t & 63;
    const int wr = wave >> 2, wc = wave & 3;
    const int m0 = blockIdx.x * 128;
    const int mlo = lane & 15, kq = lane >> 4;

    f32x4 acc[4][4] = {};

    for (int k0 = 0; k0 < IN_DIM; k0 += 32) {
        #pragma unroll
        for (int p = 0; p < 2; ++p) {
            int idx = p * 512 + t;
            int r = idx >> 3, c4 = idx & 7;
            int gr = m0 + r; if (gr >= M) gr = M - 1;
            const float4 v = *reinterpret_cast<const float4*>(&A[(size_t)gr * IN_DIM + k0 + c4 * 4]);
            ushort4 u;
            u.x = f2bf(v.x); u.y = f2bf(v.y); u.z = f2bf(v.z); u.w = f2bf(v.w);
            *reinterpret_cast<ushort4*>(&lA[r * 32 + c4 * 4]) = u;
        }
        #pragma unroll
        for (int p = 0; p < 2; ++p) {
            int idx = p * 512 + t;
            int n = idx >> 2, c8 = idx & 3;
            const uint4 v = *reinterpret_cast<const uint4*>(&Wt[(size_t)n * IN_DIM + k0 + c8 * 8]);
            *reinterpret_cast<uint4*>(&lB[n * 32 + c8 * 8]) = v;
        }
        __syncthreads();

        bf16x8 af[4], bfr[4];
        #pragma unroll
        for (int mt = 0; mt < 4; ++mt)
            af[mt] = *reinterpret_cast<const bf16x8*>(&lA[(wr * 64 + mt * 16 + mlo) * 32 + kq * 8]);
        #pragma unroll
        for (int nt = 0; nt < 4; ++nt)
            bfr[nt] = *reinterpret_cast<const bf16x8*>(&lB[(wc * 64 + nt * 16 + mlo) * 32 + kq * 8]);
        #pragma unroll
        for (int mt = 0; mt < 4; ++mt)
            #pragma unroll
            for (int nt = 0; nt < 4; ++nt)
                acc[mt][nt] = __builtin_amdgcn_mfma_f32_16x16x32_bf16(af[mt], bfr[nt], acc[mt][nt], 0, 0, 0);
        __syncthreads();
    }

    #pragma unroll
    for (int mt = 0; mt < 4; ++mt) {
        #pragma unroll
        for (int nt = 0; nt < 4; ++nt) {
            #pragma unroll
            for (int i = 0; i < 4; ++i) {
                int row = m0 + wr * 64 + mt * 16 + kq * 4 + i;
                int col = wc * 64 + nt * 16 + mlo;
                if (row < M) xw[(size_t)row * OUT_DIM + col] = f2bf(acc[mt][nt][i]);
            }
        }
    }
}

// ---------------- bucket histogram (LDS pre-aggregated) ------------------------
// 8192 edges per block, LDS hist over NB buckets, flush nonzero
__global__ void k_bhist(const int* __restrict__ rows, int* __restrict__ bcnt,
                        int E, int NB) {
    __shared__ int h[MAX_NB];
    for (int i = threadIdx.x; i < NB; i += 256) h[i] = 0;
    __syncthreads();
    int b0 = blockIdx.x * 8192;
    #pragma unroll
    for (int j = 0; j < 8; ++j) {
        int i = b0 + j * 1024 + threadIdx.x * 4;
        if (i + 4 <= E) {
            int4 r = *reinterpret_cast<const int4*>(&rows[i]);
            atomicAdd(&h[r.x >> 6], 1);
            atomicAdd(&h[r.y >> 6], 1);
            atomicAdd(&h[r.z >> 6], 1);
            atomicAdd(&h[r.w >> 6], 1);
        } else {
            for (int q = i; q < E; ++q) atomicAdd(&h[rows[q] >> 6], 1);
        }
    }
    __syncthreads();
    for (int i = threadIdx.x; i < NB; i += 256)
        if (h[i]) atomicAdd(&bcnt[i], h[i]);
}

// ---------------- single-block scan over NB bucket counts ---------------------
__global__ void k_bscan(const int* __restrict__ bcnt, int* __restrict__ bstart,
                        int* __restrict__ bcur, int NB, int E) {
    int t = threadIdx.x;
    const int PER = (MAX_NB + 255) / 256;    // 7
    int v[PER]; int s = 0;
    #pragma unroll
    for (int j = 0; j < PER; ++j) {
        int i = t * PER + j;
        v[j] = (i < NB) ? bcnt[i] : 0;
        s += v[j];
    }
    __shared__ int sh[256];
    sh[t] = s; __syncthreads();
    for (int off = 1; off < 256; off <<= 1) {
        int x = (t >= off) ? sh[t - off] : 0;
        __syncthreads();
        sh[t] += x;
        __syncthreads();
    }
    int ex = sh[t] - s;
    #pragma unroll
    for (int j = 0; j < PER; ++j) {
        int i = t * PER + j;
        if (i < NB) { bstart[i] = ex; bcur[i] = ex; ex += v[j]; }
    }
    if (t == 255) bstart[NB] = E;
}

// ---------------- bucket scatter: pack (rowres<<17 | col, val) -----------------
__global__ void k_bscatter(const int* __restrict__ rows, const int* __restrict__ cols,
                           const float* __restrict__ vals, int* __restrict__ bcur,
                           int2* __restrict__ ebuf, int E) {
    int i = (blockIdx.x * 256 + threadIdx.x) * 4;
    if (i + 4 <= E) {
        int4 r = *reinterpret_cast<const int4*>(&rows[i]);
        int4 c = *reinterpret_cast<const int4*>(&cols[i]);
        float4 v = *reinterpret_cast<const float4*>(&vals[i]);
        int p0 = atomicAdd(&bcur[r.x >> 6], 1);
        ebuf[p0] = make_int2(c.x | ((r.x & 63) << 17), __float_as_int(v.x));
        int p1 = atomicAdd(&bcur[r.y >> 6], 1);
        ebuf[p1] = make_int2(c.y | ((r.y & 63) << 17), __float_as_int(v.y));
        int p2 = atomicAdd(&bcur[r.z >> 6], 1);
        ebuf[p2] = make_int2(c.z | ((r.z & 63) << 17), __float_as_int(v.z));
        int p3 = atomicAdd(&bcur[r.w >> 6], 1);
        ebuf[p3] = make_int2(c.w | ((r.w & 63) << 17), __float_as_int(v.w));
    } else {
        for (int j = i; j < E; ++j) {
            int p = atomicAdd(&bcur[rows[j] >> 6], 1);
            ebuf[p] = make_int2(cols[j] | ((rows[j] & 63) << 17), __float_as_int(vals[j]));
        }
    }
}

// ---------------- per-bucket LDS aggregation + fused epilogue ------------------
// one block per bucket; 64 rows x 256 dims fp32 in 64KB LDS (2 blocks/CU).
// LDS layout swizzled: acc[row*256 + j*64 + lane] holds dim (4*lane + j)
//   -> all DS ops hit bank lane%32 (2-way, free per m136).
__launch_bounds__(256, 2)
__global__ void k_bagg(const unsigned short* __restrict__ xw,
                       const int2* __restrict__ ebuf,
                       const int* __restrict__ bstart,
                       const float* __restrict__ skipw,
                       const float* __restrict__ bias,
                       float* __restrict__ out, int M) {
    __shared__ float acc[BROWS * 256];   // 64 KB
    const int b = blockIdx.x;
    const int t = threadIdx.x, wave = t >> 6, lane = t & 63;

    for (int i = t; i < BROWS * 256; i += 256) acc[i] = 0.f;
    __syncthreads();

    const int s = bstart[b], e = bstart[b + 1];
    const int d4 = lane * 4;
    constexpr int U = 8;

    for (int base = s + wave * U; base < e; base += 4 * U) {
        int2 w[U];
        #pragma unroll
        for (int u = 0; u < U; ++u) {
            int idx = base + u;
            w[u] = (idx < e) ? ebuf[idx] : make_int2(0, 0);   // val=0 -> no-op
        }
        ushort4 g[U];
        #pragma unroll
        for (int u = 0; u < U; ++u) {
            int col = w[u].x & 0x1FFFF;
            g[u] = *reinterpret_cast<const ushort4*>(&xw[(size_t)col * OUT_DIM + d4]);
        }
        #pragma unroll
        for (int u = 0; u < U; ++u) {
            float val = __int_as_float(w[u].y);
            int rbase = (w[u].x >> 17) * 256 + lane;
            atomicAdd(&acc[rbase      ], val * bf2f(g[u].x));
            atomicAdd(&acc[rbase +  64], val * bf2f(g[u].y));
            atomicAdd(&acc[rbase + 128], val * bf2f(g[u].z));
            atomicAdd(&acc[rbase + 192], val * bf2f(g[u].w));
        }
    }
    __syncthreads();

    // epilogue: wave handles 16 rows
    float4 sw = *reinterpret_cast<const float4*>(&skipw[d4]);
    float4 bi = *reinterpret_cast<const float4*>(&bias[d4]);
    for (int rr = 0; rr < 16; ++rr) {
        int r = wave * 16 + rr;
        int node = b * BROWS + r;
        if (node >= M) break;
        ushort4 xi = *reinterpret_cast<const ushort4*>(&xw[(size_t)node * OUT_DIM + d4]);
        float4 o;
        o.x = selu(acc[r * 256 + lane      ] + bf2f(xi.x) * sw.x + bi.x);
        o.y = selu(acc[r * 256 + lane +  64] + bf2f(xi.y) * sw.y + bi.y);
        o.z = selu(acc[r * 256 + lane + 128] + bf2f(xi.z) * sw.z + bi.z);
        o.w = selu(acc[r * 256 + lane + 192] + bf2f(xi.w) * sw.w + bi.w);
        *reinterpret_cast<float4*>(&out[(size_t)node * OUT_DIM + d4]) = o;
    }
}

extern "C" void kernel_launch(void* const* d_in, const int* in_sizes, int n_in,
                              void* d_out, int out_size, void* d_ws, size_t ws_size,
                              hipStream_t stream) {
    const float* features = (const float*)d_in[0];
    const int*   adj_rows = (const int*)d_in[1];
    const int*   adj_cols = (const int*)d_in[2];
    const float* adj_vals = (const float*)d_in[3];
    const float* Wk       = (const float*)d_in[4];
    const float* bias     = (const float*)d_in[5];
    const float* skipw    = (const float*)d_in[6];
    float* out = (float*)d_out;

    const int M = in_sizes[0] / IN_DIM;     // 100000
    const int E = in_sizes[1];              // 3200000
    const int NB = (M + BROWS - 1) / BROWS; // 1563

    char* w = (char*)d_ws;
    size_t off = 0;
    auto carve = [&](size_t bytes) -> void* {
        void* p = w + off;
        off = (off + bytes + 255) & ~(size_t)255;
        return p;
    };
    unsigned short* xw = (unsigned short*)carve((size_t)M * OUT_DIM * 2);    // 51.2 MB
    unsigned short* Wt = (unsigned short*)carve((size_t)IN_DIM * OUT_DIM * 2);
    int*  bcnt   = (int*)carve((size_t)NB * 4);
    int*  bstart = (int*)carve((size_t)(NB + 1) * 4);
    int*  bcur   = (int*)carve((size_t)NB * 4);
    int2* ebuf   = (int2*)carve((size_t)E * 8);                              // 25.6 MB

    hipMemsetAsync(bcnt, 0, (size_t)NB * 4, stream);

    k_convW<<<(IN_DIM * OUT_DIM + 255) / 256, 256, 0, stream>>>(Wk, Wt);
    k_gemm<<<(M + 127) / 128, 512, 0, stream>>>(features, Wt, xw, M);

    k_bhist<<<(E + 8191) / 8192, 256, 0, stream>>>(adj_rows, bcnt, E, NB);
    k_bscan<<<1, 256, 0, stream>>>(bcnt, bstart, bcur, NB, E);
    k_bscatter<<<(E / 4 + 255) / 256, 256, 0, stream>>>(adj_rows, adj_cols, adj_vals, bcur, ebuf, E);

    k_bagg<<<NB, 256, 0, stream>>>(xw, ebuf, bstart, skipw, bias, out, M);
}